// Round 3
// baseline (1933.513 us; speedup 1.0000x reference)
//
#include <hip/hip_runtime.h>
#include <hip/hip_cooperative_groups.h>
#include <math.h>

namespace cg = cooperative_groups;

#define HW 65536
#define NC 10
#define NT 12
#define LAMBDA_F 0.05f
#define PI_F 3.14159265358979323846f
// XOR-swizzle for wave-private LDS fft scratch
#define SWZ(i) ((i) ^ ((i) >> 4))

__device__ __forceinline__ float2 cadd(float2 a, float2 b){ return make_float2(a.x+b.x, a.y+b.y); }
__device__ __forceinline__ float2 csub(float2 a, float2 b){ return make_float2(a.x-b.x, a.y-b.y); }
__device__ __forceinline__ float2 cmul(float2 a, float2 b){ return make_float2(a.x*b.x-a.y*b.y, a.x*b.y+a.y*b.x); }
// conj(a)*b
__device__ __forceinline__ float2 cmulj(float2 a, float2 b){ return make_float2(a.x*b.x+a.y*b.y, a.x*b.y-a.y*b.x); }
__device__ __forceinline__ float2 cscale(float2 a, float s){ return make_float2(a.x*s, a.y*s); }

template<int SIGN>
__device__ __forceinline__ void radix4_nt(float2& a0, float2& a1, float2& a2, float2& a3){
  float2 t0=cadd(a0,a2), t1=csub(a0,a2), t2=cadd(a1,a3), t3=csub(a1,a3);
  float2 t3r;
  if constexpr (SIGN < 0) t3r = make_float2(t3.y, -t3.x); else t3r = make_float2(-t3.y, t3.x);
  a0=cadd(t0,t2); a1=cadd(t1,t3r); a2=csub(t0,t2); a3=csub(t1,t3r);
}

template<int SIGN>
__device__ __forceinline__ float2 twl(const float2* tw, int e){
  float2 w = tw[e];
  if constexpr (SIGN > 0) w.y = -w.y;
  return w;
}

template<int SIGN>
__device__ __forceinline__ void radix4_tw(float2& a0, float2& a1, float2& a2, float2& a3,
                                          const float2* tw, int e){
  float2 w1 = twl<SIGN>(tw, e);
  float2 w2 = cmul(w1, w1);
  float2 w3 = cmul(w1, w2);
  a1 = cmul(a1, w1); a2 = cmul(a2, w2); a3 = cmul(a3, w3);
  radix4_nt<SIGN>(a0, a1, a2, a3);
}

// 256-pt Stockham radix-4 FFT, natural order in/out, unnormalized.
// BARRIER-FREE: b0/b1 must be private to the calling wave (64 lanes).
template<int SIGN>
__device__ __forceinline__ void fft256(float2* b0, float2* b1, const float2* tw, int j,
                                       float2& x0, float2& x1, float2& x2, float2& x3){
  radix4_nt<SIGN>(x0,x1,x2,x3);
  b0[SWZ(4*j)]=x0; b0[SWZ(4*j+1)]=x1; b0[SWZ(4*j+2)]=x2; b0[SWZ(4*j+3)]=x3;
  __builtin_amdgcn_sched_barrier(0);
  x0=b0[SWZ(j)]; x1=b0[SWZ(j+64)]; x2=b0[SWZ(j+128)]; x3=b0[SWZ(j+192)];
  __builtin_amdgcn_sched_barrier(0);
  radix4_tw<SIGN>(x0,x1,x2,x3, tw, (j&3)<<4);
  { int i=((j>>2)<<4)+(j&3); b1[SWZ(i)]=x0; b1[SWZ(i+4)]=x1; b1[SWZ(i+8)]=x2; b1[SWZ(i+12)]=x3; }
  __builtin_amdgcn_sched_barrier(0);
  x0=b1[SWZ(j)]; x1=b1[SWZ(j+64)]; x2=b1[SWZ(j+128)]; x3=b1[SWZ(j+192)];
  __builtin_amdgcn_sched_barrier(0);
  radix4_tw<SIGN>(x0,x1,x2,x3, tw, (j&15)<<2);
  { int i=((j>>4)<<6)+(j&15); b0[SWZ(i)]=x0; b0[SWZ(i+16)]=x1; b0[SWZ(i+32)]=x2; b0[SWZ(i+48)]=x3; }
  __builtin_amdgcn_sched_barrier(0);
  x0=b0[SWZ(j)]; x1=b0[SWZ(j+64)]; x2=b0[SWZ(j+128)]; x3=b0[SWZ(j+192)];
  __builtin_amdgcn_sched_barrier(0);
  radix4_tw<SIGN>(x0,x1,x2,x3, tw, j);
}

__device__ __forceinline__ void tw_init(float2* tw, int tid){
  float s, c;
  __sincosf(-2.0f*PI_F*(float)tid*(1.0f/256.0f), &s, &c);
  tw[tid] = make_float2(c, s);
}

// Reconstruct alpha_{it-1}, beta_{it-1} (and the rs chain) from reduced scalars.
// scal: [0]=rs0 ; per k: [8+8k]=pAp.re [+1]=pAp.im [+2]=rAp.re [+3]=rAp.im [+4]=|Ap|^2
// Exact expansion: rs_{k+1} = rs_k - 2 Re(alpha*rAp) + |alpha|^2 |Ap|^2.
__device__ __forceinline__ void cg_scalars(const float* __restrict__ scal, int it,
                                           float& a_re, float& a_im, float& beta){
  float rs = scal[0]; a_re = 0.f; a_im = 0.f; beta = 0.f;
  for (int k = 0; k < it; k++){
    float pr = scal[8+8*k+0], pi = scal[8+8*k+1];
    float rr_ = scal[8+8*k+2], ri_ = scal[8+8*k+3];
    float aa = scal[8+8*k+4];
    float den = pr*pr + pi*pi;
    a_re =  rs*pr/den;
    a_im = -rs*pi/den;
    float re_ = a_re*rr_ - a_im*ri_;   // Re(alpha * rAp)
    float rs_next = rs - 2.0f*re_ + (a_re*a_re + a_im*a_im)*aa;
    beta = rs_next/rs;
    rs = rs_next;
  }
}

// =====================================================================
// Cooperative mega-kernel: whole pipeline, 34 grid syncs.
// Layouts: bufA = transposed spectra A_T[pl][kx][y]; bufB = row-major [pl][y][*].
// =====================================================================
__global__ __launch_bounds__(256, 3) void k_mega(
    const float2* __restrict__ y, const float2* __restrict__ mo,
    const float2* __restrict__ sens, const float2* __restrict__ Lt,
    const float* __restrict__ mask,
    float* __restrict__ W9, float2* __restrict__ bufA, float2* __restrict__ bufB,
    float2* __restrict__ p0, float2* __restrict__ p1,
    float2* __restrict__ r0, float2* __restrict__ r1,
    float2* __restrict__ Apb, float2* __restrict__ z, float* __restrict__ scal)
{
  cg::grid_group grid = cg::this_grid();
  __shared__ float2 tile[12][256];   // 24 KB
  __shared__ float2 sc[4][256];      // 8 KB
  __shared__ float2 tw[256];         // 2 KB
  __shared__ float  red5[4][5];
  int tid = threadIdx.x, g = tid >> 6, j = tid & 63;
  int bid = blockIdx.x, nb = gridDim.x;
  tw_init(tw, tid);
  __syncthreads();

  // ---------------- S0: W9 precompute + g = D*sum_t conj(L) y + scal zero
  if (bid == 0 && tid < 128) scal[tid] = 0.0f;
  for (int u = bid; u < 2816; u += nb){
    if (u < 256){
      int kx = u, ky = tid;
      int mx = (kx + 128) & 255, my = (ky + 128) & 255;
      float d0=0.f,d1=0.f,d2=0.f;
      float2 o01=make_float2(0,0), o02=make_float2(0,0), o12=make_float2(0,0);
      for (int t = 0; t < NT; t++){
        float m = mask[t*HW + my*256 + mx];
        float2 l0 = Lt[t*3+0], l1 = Lt[t*3+1], l2 = Lt[t*3+2];
        d0 += m*(l0.x*l0.x + l0.y*l0.y);
        d1 += m*(l1.x*l1.x + l1.y*l1.y);
        d2 += m*(l2.x*l2.x + l2.y*l2.y);
        o01 = cadd(o01, cscale(cmulj(l0,l1), m));
        o02 = cadd(o02, cscale(cmulj(l0,l2), m));
        o12 = cadd(o12, cscale(cmulj(l1,l2), m));
      }
      const float nrm = 1.0f/65536.0f;
      int idx = kx*256 + ky;
      W9[idx]      = d0*nrm;  W9[idx+HW]   = d1*nrm;  W9[idx+2*HW] = d2*nrm;
      W9[idx+3*HW] = o01.x*nrm; W9[idx+4*HW] = o01.y*nrm;
      W9[idx+5*HW] = o02.x*nrm; W9[idx+6*HW] = o02.y*nrm;
      W9[idx+7*HW] = o12.x*nrm; W9[idx+8*HW] = o12.y*nrm;
    } else {
      int idx = (u-256)*256 + tid;
      int c = idx >> 16, pix = idx & (HW-1);
      int xx = pix & 255, yy2 = pix >> 8;
      float sg = ((xx + yy2) & 1) ? -1.0f : 1.0f;
      float2 a0=make_float2(0,0), a1=make_float2(0,0), a2=make_float2(0,0);
      for (int t = 0; t < NT; t++){
        float2 yv = y[((size_t)(t*NC + c))*HW + pix];
        a0 = cadd(a0, cmulj(Lt[t*3+0], yv));
        a1 = cadd(a1, cmulj(Lt[t*3+1], yv));
        a2 = cadd(a2, cmulj(Lt[t*3+2], yv));
      }
      bufB[((size_t)(c*3+0))*HW + pix] = cscale(a0, sg);
      bufB[((size_t)(c*3+1))*HW + pix] = cscale(a1, sg);
      bufB[((size_t)(c*3+2))*HW + pix] = cscale(a2, sg);
    }
  }
  grid.sync();

  // ---------------- S1: row ifft (SIGN=-1) bufB -> bufA (transposed)
  for (int u = bid; u < 960; u += nb){
    int pl = u >> 5, ri = u & 31;
    const float2* src = bufB + (size_t)pl*HW;
    for (int rr = 0; rr < 2; rr++){
      int lr = g + rr*4, row = ri*8 + lr;
      const float2* s = src + row*256;
      float2 x0=s[j], x1=s[j+64], x2=s[j+128], x3=s[j+192];
      fft256<-1>(tile[lr], sc[g], tw, j, x0,x1,x2,x3);
      tile[lr][j]=x0; tile[lr][j+64]=x1; tile[lr][j+128]=x2; tile[lr][j+192]=x3;
    }
    __syncthreads();
    float2* dT = bufA + (size_t)pl*HW;
    int yo2 = (tid&3)*2, kxo = tid>>2;
    #pragma unroll
    for (int kb = 0; kb < 4; kb++){
      int kx = kb*64 + kxo;
      float2 a = tile[yo2][kx], b = tile[yo2+1][kx];
      *(float4*)(dT + (size_t)kx*256 + ri*8 + yo2) = make_float4(a.x,a.y,b.x,b.y);
    }
    __syncthreads();
  }
  grid.sync();

  // ---------------- S2: col ifft (SIGN=-1) bufA lines -> bufB row-major
  for (int u = bid; u < 1920; u += nb){
    int pl = u >> 6, kg = u & 63; int kxbase = kg*4;
    { const float4* s4 = (const float4*)(bufA + (size_t)pl*HW + (size_t)kxbase*256);
      float4 v0 = s4[tid], v1 = s4[tid+256];
      int lid0 = tid>>7, off0 = tid&127;
      *(float4*)&tile[lid0][off0*2] = v0;
      *(float4*)&tile[lid0+2][off0*2] = v1;
    }
    __syncthreads();
    { float2 x0=tile[g][j], x1=tile[g][j+64], x2=tile[g][j+128], x3=tile[g][j+192];
      fft256<-1>(tile[g], sc[g], tw, j, x0,x1,x2,x3);
      tile[g][j]=x0; tile[g][j+64]=x1; tile[g][j+128]=x2; tile[g][j+192]=x3;
    }
    __syncthreads();
    float2* dst = bufB + (size_t)pl*HW;
    int kxo2 = (tid&1)*2, yy = tid>>1;
    #pragma unroll
    for (int yb = 0; yb < 2; yb++){
      int yc = yb*128 + yy;
      float2 a = tile[kxo2][yc], b = tile[kxo2+1][yc];
      *(float4*)(dst + (size_t)yc*256 + kxbase + kxo2) = make_float4(a.x,a.y,b.x,b.y);
    }
    __syncthreads();
  }
  grid.sync();

  // ---------------- S3: b = D*sum_c conj(S)*bufB + lambda*mo ; p0=r0=b ; z=0 ; rs0
  for (int u = bid; u < 768; u += nb){
    int idx = u*256 + tid;
    int s = idx >> 16, pix = idx & (HW-1);
    int xx = pix & 255, yy2 = pix >> 8;
    float sg = ((xx + yy2) & 1) ? -1.0f : 1.0f;
    float2 accv = make_float2(0,0);
    for (int c = 0; c < NC; c++)
      accv = cadd(accv, cmulj(sens[(size_t)c*HW + pix], bufB[((size_t)(c*3+s))*HW + pix]));
    float2 b = cadd(cscale(accv, sg), cscale(mo[idx], LAMBDA_F));
    p0[idx] = b; r0[idx] = b; z[idx] = make_float2(0,0);
    float part = b.x*b.x + b.y*b.y;
    for (int off = 32; off; off >>= 1) part += __shfl_down(part, off);
    if (j == 0) red5[g][0] = part;
    __syncthreads();
    if (tid == 0) atomicAdd(&scal[0], red5[0][0]+red5[1][0]+red5[2][0]+red5[3][0]);
    __syncthreads();
  }
  grid.sync();

  // ---------------- CG iterations
  for (int it = 0; it < 10; it++){
    const float2* pprev = ((it-1)&1) ? p1 : p0;   // valid for it>=1
    const float2* rprev = ((it-1)&1) ? r1 : r0;
    float2* pw = (it&1) ? p1 : p0;                // p_it
    float2* rw = (it&1) ? r1 : r0;                // r_it
    float a_re, a_im, beta;
    if (it > 0) cg_scalars(scal, it, a_re, a_im, beta);

    // ---- Phase A: (p,r,z update) + sens-mult + row fft (SIGN=+1) -> bufA (T)
    for (int u = bid; u < 960; u += nb){
      int pl = u >> 5, ri = u & 31;
      int c = pl/3, sp = pl - c*3;
      const float2* Sp = sens + (size_t)c*HW;
      for (int rr = 0; rr < 2; rr++){
        int lr = g + rr*4, row = ri*8 + lr;
        int base = row*256;
        float2 pv[4];
        if (it == 0){
          const float2* P = p0 + (size_t)sp*HW + base;
          pv[0]=P[j]; pv[1]=P[j+64]; pv[2]=P[j+128]; pv[3]=P[j+192];
        } else {
          const float2* Pp = pprev + (size_t)sp*HW + base;
          const float2* Rp = rprev + (size_t)sp*HW + base;
          const float2* Aq = Apb + (size_t)sp*HW + base;
          #pragma unroll
          for (int q = 0; q < 4; q++){
            int x = j + 64*q;
            float2 pe = Pp[x], re_ = Rp[x], ae = Aq[x];
            float2 rnew = make_float2(re_.x - (a_re*ae.x - a_im*ae.y),
                                      re_.y - (a_re*ae.y + a_im*ae.x));
            pv[q] = make_float2(rnew.x + beta*pe.x, rnew.y + beta*pe.y);
            if (c == 0){
              size_t ob = (size_t)sp*HW + base + x;
              rw[ob] = rnew;
              pw[ob] = pv[q];
              float2 ze = z[ob];
              z[ob] = make_float2(ze.x + a_re*pe.x - a_im*pe.y,
                                  ze.y + a_re*pe.y + a_im*pe.x);
            }
          }
        }
        float2 x0 = cmul(Sp[base+j],     pv[0]);
        float2 x1 = cmul(Sp[base+j+64],  pv[1]);
        float2 x2 = cmul(Sp[base+j+128], pv[2]);
        float2 x3 = cmul(Sp[base+j+192], pv[3]);
        fft256<1>(tile[lr], sc[g], tw, j, x0,x1,x2,x3);
        tile[lr][j]=x0; tile[lr][j+64]=x1; tile[lr][j+128]=x2; tile[lr][j+192]=x3;
      }
      __syncthreads();
      float2* dT = bufA + (size_t)pl*HW;
      int yo2 = (tid&3)*2, kxo = tid>>2;
      #pragma unroll
      for (int kb = 0; kb < 4; kb++){
        int kx = kb*64 + kxo;
        float2 a = tile[yo2][kx], b = tile[yo2+1][kx];
        *(float4*)(dT + (size_t)kx*256 + ri*8 + yo2) = make_float4(a.x,a.y,b.x,b.y);
      }
      __syncthreads();
    }
    grid.sync();

    // ---- Phase B: col fft (+1) -> W combine -> col ifft (-1), bufA -> bufB
    for (int u = bid; u < 640; u += nb){
      int cc = u >> 6, kg = u & 63; int kxbase = kg*4;
      for (int i = tid; i < 1536; i += 256){
        int lid = i >> 7, off = i & 127;
        int s = lid >> 2, kxo = lid & 3;
        const float4* s4 = (const float4*)(bufA + ((size_t)(cc*3+s))*HW + (size_t)(kxbase+kxo)*256);
        *(float4*)&tile[lid][off*2] = s4[off];
      }
      __syncthreads();
      int kx = kxbase + g;
      float2 X[3][4];
      #pragma unroll
      for (int s = 0; s < 3; s++){
        int lid = s*4 + g;
        float2 x0=tile[lid][j], x1=tile[lid][j+64], x2=tile[lid][j+128], x3=tile[lid][j+192];
        fft256<1>(tile[lid], sc[g], tw, j, x0,x1,x2,x3);
        X[s][0]=x0; X[s][1]=x1; X[s][2]=x2; X[s][3]=x3;
      }
      float2 U[3][4];
      #pragma unroll
      for (int q = 0; q < 4; q++){
        int wi = kx*256 + j + 64*q;
        float d0 = W9[wi], d1 = W9[wi+HW], d2 = W9[wi+2*HW];
        float2 o01 = make_float2(W9[wi+3*HW], W9[wi+4*HW]);
        float2 o02 = make_float2(W9[wi+5*HW], W9[wi+6*HW]);
        float2 o12 = make_float2(W9[wi+7*HW], W9[wi+8*HW]);
        float2 v0 = X[0][q], v1 = X[1][q], v2 = X[2][q];
        U[0][q] = cadd(cadd(cscale(v0,d0), cmul(o01,v1)), cmul(o02,v2));
        U[1][q] = cadd(cadd(cmulj(o01,v0), cscale(v1,d1)), cmul(o12,v2));
        U[2][q] = cadd(cadd(cmulj(o02,v0), cmulj(o12,v1)), cscale(v2,d2));
      }
      #pragma unroll
      for (int s = 0; s < 3; s++){
        int lid = s*4 + g;
        float2 x0=U[s][0], x1=U[s][1], x2=U[s][2], x3=U[s][3];
        fft256<-1>(tile[lid], sc[g], tw, j, x0,x1,x2,x3);
        tile[lid][j]=x0; tile[lid][j+64]=x1; tile[lid][j+128]=x2; tile[lid][j+192]=x3;
      }
      __syncthreads();
      int kxo2 = (tid&1)*2, yy = tid>>1;
      for (int s = 0; s < 3; s++){
        float2* dst = bufB + ((size_t)(cc*3+s))*HW;
        #pragma unroll
        for (int yb = 0; yb < 2; yb++){
          int yc = yb*128 + yy;
          float2 a = tile[s*4+kxo2][yc], b = tile[s*4+kxo2+1][yc];
          *(float4*)(dst + (size_t)yc*256 + kxbase + kxo2) = make_float4(a.x,a.y,b.x,b.y);
        }
      }
      __syncthreads();
    }
    grid.sync();

    // ---- Phase C: row ifft (-1) + conj(S) coil-combine + lambda*p -> Ap; reduce pAp,rAp,|Ap|^2
    {
      const float2* pc = (it&1) ? p1 : p0;
      const float2* rc = (it&1) ? r1 : r0;
      for (int u = bid; u < 768; u += nb){
        int row = u & 255, s = u >> 8;
        float2 acc0=make_float2(0,0), acc1=acc0, acc2=acc0, acc3=acc0;
        for (int ccq = 0; ccq < 3; ccq++){
          int c = ccq*4 + g;
          if (c < NC){
            const float2* src = bufB + ((size_t)(c*3+s))*HW + row*256;
            float2 x0=src[j], x1=src[j+64], x2=src[j+128], x3=src[j+192];
            fft256<-1>(tile[g], sc[g], tw, j, x0,x1,x2,x3);
            const float2* Sc = sens + (size_t)c*HW + row*256;
            acc0 = cadd(acc0, cmulj(Sc[j],     x0));
            acc1 = cadd(acc1, cmulj(Sc[j+64],  x1));
            acc2 = cadd(acc2, cmulj(Sc[j+128], x2));
            acc3 = cadd(acc3, cmulj(Sc[j+192], x3));
          }
        }
        tile[4+g][j]=acc0; tile[4+g][j+64]=acc1; tile[4+g][j+128]=acc2; tile[4+g][j+192]=acc3;
        __syncthreads();
        int k = tid;
        size_t ob = (size_t)s*HW + row*256 + k;
        float2 a = cadd(cadd(tile[4][k], tile[5][k]), cadd(tile[6][k], tile[7][k]));
        float2 pv = pc[ob];
        float2 ap = cadd(a, cscale(pv, LAMBDA_F));
        Apb[ob] = ap;
        float2 rv = rc[ob];
        float s0 = pv.x*ap.x + pv.y*ap.y;   // pAp.re
        float s1 = pv.x*ap.y - pv.y*ap.x;   // pAp.im
        float s2 = rv.x*ap.x + rv.y*ap.y;   // rAp.re
        float s3 = rv.x*ap.y - rv.y*ap.x;   // rAp.im
        float s4 = ap.x*ap.x + ap.y*ap.y;   // |Ap|^2
        for (int off = 32; off; off >>= 1){
          s0 += __shfl_down(s0, off); s1 += __shfl_down(s1, off);
          s2 += __shfl_down(s2, off); s3 += __shfl_down(s3, off);
          s4 += __shfl_down(s4, off);
        }
        if (j == 0){ red5[g][0]=s0; red5[g][1]=s1; red5[g][2]=s2; red5[g][3]=s3; red5[g][4]=s4; }
        __syncthreads();
        if (tid == 0){
          atomicAdd(&scal[8+8*it+0], red5[0][0]+red5[1][0]+red5[2][0]+red5[3][0]);
          atomicAdd(&scal[8+8*it+1], red5[0][1]+red5[1][1]+red5[2][1]+red5[3][1]);
          atomicAdd(&scal[8+8*it+2], red5[0][2]+red5[1][2]+red5[2][2]+red5[3][2]);
          atomicAdd(&scal[8+8*it+3], red5[0][3]+red5[1][3]+red5[2][3]+red5[3][3]);
          atomicAdd(&scal[8+8*it+4], red5[0][4]+red5[1][4]+red5[2][4]+red5[3][4]);
        }
        __syncthreads();
      }
    }
    grid.sync();
  }

  // ---------------- Final: z += alpha_9 * p_9
  {
    float a_re, a_im, beta;
    cg_scalars(scal, 10, a_re, a_im, beta);
    const float2* p9 = p1;   // it=9 -> odd
    for (int u = bid; u < 768; u += nb){
      int idx = u*256 + tid;
      float2 pe = p9[idx], ze = z[idx];
      z[idx] = make_float2(ze.x + a_re*pe.x - a_im*pe.y,
                           ze.y + a_re*pe.y + a_im*pe.x);
    }
  }
}

// =====================================================================
// Fallback path: round-2 kernel sequence (used only if coop launch fails)
// =====================================================================
__global__ __launch_bounds__(256) void k_precompute_W(const float* __restrict__ mask,
                                                      const float2* __restrict__ Lt,
                                                      float* __restrict__ W9,
                                                      float* __restrict__ scal){
  __shared__ float2 Ls[NT*3];
  int tid = threadIdx.x;
  if (tid < NT*3) Ls[tid] = Lt[tid];
  if (blockIdx.x == 0 && tid < 64) scal[tid] = 0.0f;
  __syncthreads();
  int idx = blockIdx.x*256 + tid;
  int kx = idx >> 8, ky = idx & 255;
  int mx = (kx + 128) & 255, my = (ky + 128) & 255;
  float d0=0.f, d1=0.f, d2=0.f;
  float2 o01=make_float2(0,0), o02=make_float2(0,0), o12=make_float2(0,0);
  for (int t = 0; t < NT; t++){
    float m = mask[t*HW + my*256 + mx];
    float2 l0 = Ls[t*3+0], l1 = Ls[t*3+1], l2 = Ls[t*3+2];
    d0 += m*(l0.x*l0.x + l0.y*l0.y);
    d1 += m*(l1.x*l1.x + l1.y*l1.y);
    d2 += m*(l2.x*l2.x + l2.y*l2.y);
    o01 = cadd(o01, cscale(cmulj(l0,l1), m));
    o02 = cadd(o02, cscale(cmulj(l0,l2), m));
    o12 = cadd(o12, cscale(cmulj(l1,l2), m));
  }
  const float nrm = 1.0f/65536.0f;
  W9[idx]      = d0*nrm;  W9[idx+HW]   = d1*nrm;  W9[idx+2*HW] = d2*nrm;
  W9[idx+3*HW] = o01.x*nrm; W9[idx+4*HW] = o01.y*nrm;
  W9[idx+5*HW] = o02.x*nrm; W9[idx+6*HW] = o02.y*nrm;
  W9[idx+7*HW] = o12.x*nrm; W9[idx+8*HW] = o12.y*nrm;
}

__global__ __launch_bounds__(256) void k_compute_g(const float2* __restrict__ y,
                                                   const float2* __restrict__ Lt,
                                                   float2* __restrict__ A){
  __shared__ float2 Ls[NT*3];
  int tid = threadIdx.x;
  if (tid < NT*3) Ls[tid] = Lt[tid];
  __syncthreads();
  int idx = blockIdx.x*256 + tid;
  int c = idx >> 16, pix = idx & (HW-1);
  int xx = pix & 255, yy = pix >> 8;
  float sg = ((xx + yy) & 1) ? -1.0f : 1.0f;
  float2 a0=make_float2(0,0), a1=make_float2(0,0), a2=make_float2(0,0);
  for (int t = 0; t < NT; t++){
    float2 yv = y[((size_t)(t*NC + c))*HW + pix];
    a0 = cadd(a0, cmulj(Ls[t*3+0], yv));
    a1 = cadd(a1, cmulj(Ls[t*3+1], yv));
    a2 = cadd(a2, cmulj(Ls[t*3+2], yv));
  }
  A[((size_t)(c*3+0))*HW + pix] = cscale(a0, sg);
  A[((size_t)(c*3+1))*HW + pix] = cscale(a1, sg);
  A[((size_t)(c*3+2))*HW + pix] = cscale(a2, sg);
}

__global__ __launch_bounds__(256) void k_fft_rows_plain(const float2* __restrict__ src,
                                                        float2* __restrict__ dst){
  __shared__ float2 lds0[4][256], lds1[4][256];
  __shared__ float2 tw[256];
  int tid = threadIdx.x, g = tid >> 6, j = tid & 63;
  tw_init(tw, tid);
  __syncthreads();
  int pl = blockIdx.y, row = blockIdx.x*4 + g;
  size_t base = (size_t)pl*HW + row*256;
  float2 x0=src[base+j], x1=src[base+j+64], x2=src[base+j+128], x3=src[base+j+192];
  fft256<-1>(lds0[g], lds1[g], tw, j, x0,x1,x2,x3);
  dst[base+j]=x0; dst[base+j+64]=x1; dst[base+j+128]=x2; dst[base+j+192]=x3;
}

__global__ __launch_bounds__(256) void k_fft_rows_op(const float2* __restrict__ rbuf,
                                                     const float2* __restrict__ pprev,
                                                     float2* __restrict__ pout,
                                                     const float2* __restrict__ sens,
                                                     float2* __restrict__ dst,
                                                     const float* __restrict__ scal, int iter){
  __shared__ float2 lds0[4][256], lds1[4][256];
  __shared__ float2 tw[256];
  int tid = threadIdx.x, g = tid >> 6, j = tid & 63;
  tw_init(tw, tid);
  __syncthreads();
  int pl = blockIdx.y; int c = pl/3, sp = pl - 3*c;
  int row = blockIdx.x*4 + g;
  size_t pb = (size_t)sp*HW + row*256;
  size_t sb = (size_t)c*HW + row*256;
  float2 pv0, pv1, pv2, pv3;
  if (iter == 0){
    pv0 = pprev[pb+j]; pv1 = pprev[pb+j+64]; pv2 = pprev[pb+j+128]; pv3 = pprev[pb+j+192];
  } else {
    float beta = scal[iter] / scal[iter-1];
    pv0 = cadd(rbuf[pb+j],     cscale(pprev[pb+j],     beta));
    pv1 = cadd(rbuf[pb+j+64],  cscale(pprev[pb+j+64],  beta));
    pv2 = cadd(rbuf[pb+j+128], cscale(pprev[pb+j+128], beta));
    pv3 = cadd(rbuf[pb+j+192], cscale(pprev[pb+j+192], beta));
    if (c == 0){
      pout[pb+j] = pv0; pout[pb+j+64] = pv1; pout[pb+j+128] = pv2; pout[pb+j+192] = pv3;
    }
  }
  float2 x0 = cmul(sens[sb+j],     pv0);
  float2 x1 = cmul(sens[sb+j+64],  pv1);
  float2 x2 = cmul(sens[sb+j+128], pv2);
  float2 x3 = cmul(sens[sb+j+192], pv3);
  fft256<1>(lds0[g], lds1[g], tw, j, x0,x1,x2,x3);
  dst[(size_t)pl*HW + row*256 + j]     = x0;
  dst[(size_t)pl*HW + row*256 + j+64]  = x1;
  dst[(size_t)pl*HW + row*256 + j+128] = x2;
  dst[(size_t)pl*HW + row*256 + j+192] = x3;
}

template<int SIGN1, bool DO_W>
__global__ __launch_bounds__(256) void k_fft_cols(const float2* __restrict__ src,
                                                  float2* __restrict__ dst,
                                                  const float* __restrict__ W9){
  constexpr int NPL = DO_W ? 3 : 1;
  __shared__ float2 T[NPL][4][256];
  __shared__ float2 scl[4][256];
  __shared__ float2 tw[256];
  int tid = threadIdx.x, g = tid >> 6, j = tid & 63;
  tw_init(tw, tid);
  int colBase = blockIdx.x * 4;
  for (int s = 0; s < NPL; s++){
    int pl = DO_W ? (blockIdx.y*3 + s) : blockIdx.y;
    const float4* s4 = (const float4*)(src + (size_t)pl*HW);
    for (int step = 0; step < 2; step++){
      int rrow = step*128 + (tid >> 1);
      int cp = tid & 1;
      float4 v = s4[(size_t)rrow*128 + (colBase >> 1) + cp];
      T[s][cp*2+0][rrow] = make_float2(v.x, v.y);
      T[s][cp*2+1][rrow] = make_float2(v.z, v.w);
    }
  }
  __syncthreads();
  for (int s = 0; s < NPL; s++){
    float2 x0=T[s][g][j], x1=T[s][g][j+64], x2=T[s][g][j+128], x3=T[s][g][j+192];
    fft256<SIGN1>(T[s][g], scl[g], tw, j, x0,x1,x2,x3);
    T[s][g][j]=x0; T[s][g][j+64]=x1; T[s][g][j+128]=x2; T[s][g][j+192]=x3;
  }
  if constexpr (DO_W) {
    int kx = colBase + g;
    for (int rr = 0; rr < 4; rr++){
      int k = j + 64*rr;
      size_t wi = (size_t)kx*256 + k;
      float d0 = W9[wi], d1 = W9[wi+HW], d2 = W9[wi+2*HW];
      float2 o01 = make_float2(W9[wi+3*HW], W9[wi+4*HW]);
      float2 o02 = make_float2(W9[wi+5*HW], W9[wi+6*HW]);
      float2 o12 = make_float2(W9[wi+7*HW], W9[wi+8*HW]);
      float2 v0 = T[0][g][k], v1 = T[1][g][k], v2 = T[2][g][k];
      float2 u0 = cadd(cadd(cscale(v0,d0), cmul(o01,v1)), cmul(o02,v2));
      float2 u1 = cadd(cadd(cmulj(o01,v0), cscale(v1,d1)), cmul(o12,v2));
      float2 u2 = cadd(cadd(cmulj(o02,v0), cmulj(o12,v1)), cscale(v2,d2));
      T[0][g][k]=u0; T[1][g][k]=u1; T[2][g][k]=u2;
    }
    for (int s = 0; s < 3; s++){
      float2 x0=T[s][g][j], x1=T[s][g][j+64], x2=T[s][g][j+128], x3=T[s][g][j+192];
      fft256<-1>(T[s][g], scl[g], tw, j, x0,x1,x2,x3);
      T[s][g][j]=x0; T[s][g][j+64]=x1; T[s][g][j+128]=x2; T[s][g][j+192]=x3;
    }
  }
  __syncthreads();
  for (int s = 0; s < NPL; s++){
    int pl = DO_W ? (blockIdx.y*3 + s) : blockIdx.y;
    float4* d4 = (float4*)(dst + (size_t)pl*HW);
    for (int step = 0; step < 2; step++){
      int rrow = step*128 + (tid >> 1);
      int cp = tid & 1;
      float2 a = T[s][cp*2+0][rrow], b = T[s][cp*2+1][rrow];
      d4[(size_t)rrow*128 + (colBase >> 1) + cp] = make_float4(a.x, a.y, b.x, b.y);
    }
  }
}

__global__ __launch_bounds__(256) void k_compute_b(const float2* __restrict__ A,
                                                   const float2* __restrict__ sens,
                                                   const float2* __restrict__ mo,
                                                   float2* __restrict__ p,
                                                   float2* __restrict__ r,
                                                   float2* __restrict__ z,
                                                   float* __restrict__ scal){
  __shared__ float red[4];
  int idx = blockIdx.x*256 + threadIdx.x;
  int s = idx >> 16, pix = idx & (HW-1);
  int xx = pix & 255, yy = pix >> 8;
  float sg = ((xx + yy) & 1) ? -1.0f : 1.0f;
  float2 accv = make_float2(0,0);
  for (int c = 0; c < NC; c++)
    accv = cadd(accv, cmulj(sens[(size_t)c*HW + pix], A[((size_t)(c*3+s))*HW + pix]));
  float2 b = cadd(cscale(accv, sg), cscale(mo[idx], LAMBDA_F));
  p[idx] = b; r[idx] = b; z[idx] = make_float2(0,0);
  float part = b.x*b.x + b.y*b.y;
  for (int off = 32; off; off >>= 1) part += __shfl_down(part, off);
  int j = threadIdx.x & 63, w = threadIdx.x >> 6;
  if (j == 0) red[w] = part;
  __syncthreads();
  if (threadIdx.x == 0) atomicAdd(&scal[0], red[0]+red[1]+red[2]+red[3]);
}

__global__ __launch_bounds__(256) void k_fft_rows_acc(const float2* __restrict__ Bp,
                                                      const float2* __restrict__ sens,
                                                      const float2* __restrict__ p,
                                                      float2* __restrict__ Ap,
                                                      float* __restrict__ scal, int iter){
  __shared__ float2 lds0[4][256], lds1[4][256];
  __shared__ float2 acc[4][256];
  __shared__ float2 tw[256];
  __shared__ float2 wred[4];
  int tid = threadIdx.x, g = tid >> 6, j = tid & 63;
  tw_init(tw, tid);
  __syncthreads();
  int row = blockIdx.x, s = blockIdx.y;
  acc[g][j]=make_float2(0,0); acc[g][j+64]=make_float2(0,0);
  acc[g][j+128]=make_float2(0,0); acc[g][j+192]=make_float2(0,0);
  for (int cc = 0; cc < 3; cc++){
    int c = cc*4 + g;
    if (c < NC){
      size_t base = ((size_t)(c*3+s))*HW + row*256;
      float2 x0 = Bp[base+j], x1 = Bp[base+j+64], x2 = Bp[base+j+128], x3 = Bp[base+j+192];
      fft256<-1>(lds0[g], lds1[g], tw, j, x0,x1,x2,x3);
      size_t sb = (size_t)c*HW + row*256;
      acc[g][j]     = cadd(acc[g][j],     cmulj(sens[sb+j],     x0));
      acc[g][j+64]  = cadd(acc[g][j+64],  cmulj(sens[sb+j+64],  x1));
      acc[g][j+128] = cadd(acc[g][j+128], cmulj(sens[sb+j+128], x2));
      acc[g][j+192] = cadd(acc[g][j+192], cmulj(sens[sb+j+192], x3));
    }
  }
  __syncthreads();
  int k = tid;
  size_t ob = (size_t)s*HW + row*256 + k;
  float2 a = cadd(cadd(acc[0][k], acc[1][k]), cadd(acc[2][k], acc[3][k]));
  float2 pv = p[ob];
  float2 ap = cadd(a, cscale(pv, LAMBDA_F));
  Ap[ob] = ap;
  float2 pap = cmulj(pv, ap);
  for (int off = 32; off; off >>= 1){
    pap.x += __shfl_down(pap.x, off);
    pap.y += __shfl_down(pap.y, off);
  }
  if (j == 0) wred[g] = pap;
  __syncthreads();
  if (tid == 0){
    float2 tot = cadd(cadd(wred[0], wred[1]), cadd(wred[2], wred[3]));
    atomicAdd(&scal[16 + 2*iter],     tot.x);
    atomicAdd(&scal[16 + 2*iter + 1], tot.y);
  }
}

__global__ __launch_bounds__(256) void k_update_zr(float2* __restrict__ z,
                                                   float2* __restrict__ r,
                                                   const float2* __restrict__ p,
                                                   const float2* __restrict__ Ap,
                                                   float* __restrict__ scal, int iter){
  __shared__ float red[4];
  int idx = blockIdx.x*256 + threadIdx.x;
  float rs = scal[iter];
  float2 pap = make_float2(scal[16+2*iter], scal[16+2*iter+1]);
  float den = pap.x*pap.x + pap.y*pap.y;
  float inv = rs / den;
  float2 alpha = make_float2(pap.x*inv, -pap.y*inv);
  float2 pv = p[idx], apv = Ap[idx];
  float2 zv = cadd(z[idx], cmul(alpha, pv));
  float2 rv = csub(r[idx], cmul(alpha, apv));
  z[idx] = zv; r[idx] = rv;
  float part = rv.x*rv.x + rv.y*rv.y;
  for (int off = 32; off; off >>= 1) part += __shfl_down(part, off);
  int j = threadIdx.x & 63, w = threadIdx.x >> 6;
  if (j == 0) red[w] = part;
  __syncthreads();
  if (threadIdx.x == 0) atomicAdd(&scal[iter+1], red[0]+red[1]+red[2]+red[3]);
}

extern "C" void kernel_launch(void* const* d_in, const int* in_sizes, int n_in,
                              void* d_out, int out_size, void* d_ws, size_t ws_size,
                              hipStream_t stream){
  const float2* y    = (const float2*)d_in[0];
  const float2* mo   = (const float2*)d_in[1];
  const float2* sens = (const float2*)d_in[2];
  const float2* Lt   = (const float2*)d_in[3];
  const float*  mask = (const float*)d_in[4];

  float* w = (float*)d_ws;
  float*  scal = w;                                  // 128 floats
  float*  W9   = w + 128;                            // 9*HW floats
  float2* bufA = (float2*)(w + 128 + 9*HW);          // 30 planes
  float2* bufB = bufA + (size_t)30*HW;               // 30 planes
  float2* p0   = bufB + (size_t)30*HW;
  float2* p1   = p0 + (size_t)3*HW;
  float2* r0   = p1 + (size_t)3*HW;
  float2* r1   = r0 + (size_t)3*HW;
  float2* Apb  = r1 + (size_t)3*HW;
  float2* z    = (float2*)d_out;

  int nbmax = 0;
  hipOccupancyMaxActiveBlocksPerMultiprocessor(&nbmax, (const void*)k_mega, 256, 0);
  int gridn = nbmax > 0 ? nbmax*256 : 0;
  if (gridn > 960) gridn = 960;

  bool ok = false;
  if (gridn >= 256){
    const float2* yv = y; const float2* mov = mo; const float2* sv = sens;
    const float2* lv = Lt; const float* mk = mask;
    void* args[] = { (void*)&yv, (void*)&mov, (void*)&sv, (void*)&lv, (void*)&mk,
                     (void*)&W9, (void*)&bufA, (void*)&bufB,
                     (void*)&p0, (void*)&p1, (void*)&r0, (void*)&r1,
                     (void*)&Apb, (void*)&z, (void*)&scal };
    ok = (hipLaunchCooperativeKernel((const void*)k_mega, dim3(gridn), dim3(256),
                                     args, 0, stream) == hipSuccess);
  }

  if (!ok){
    // Fallback: round-2 sequence
    k_precompute_W<<<256, 256, 0, stream>>>(mask, Lt, W9, scal);
    k_compute_g<<<2560, 256, 0, stream>>>(y, Lt, bufA);
    k_fft_rows_plain<<<dim3(64, 30), 256, 0, stream>>>(bufA, bufB);
    k_fft_cols<-1, false><<<dim3(64, 30), 256, 0, stream>>>(bufB, bufA, nullptr);
    k_compute_b<<<768, 256, 0, stream>>>(bufA, sens, mo, p0, r0, z, scal);
    for (int it = 0; it < 10; it++){
      float2* pcur  = (it & 1) ? p1 : p0;
      float2* pprev = (it == 0) ? p0 : ((it & 1) ? p0 : p1);
      k_fft_rows_op<<<dim3(64, 30), 256, 0, stream>>>(r0, pprev, pcur, sens, bufA, scal, it);
      k_fft_cols<1, true><<<dim3(64, 10), 256, 0, stream>>>(bufA, bufB, W9);
      k_fft_rows_acc<<<dim3(256, 3), 256, 0, stream>>>(bufB, sens, pcur, Apb, scal, it);
      k_update_zr<<<768, 256, 0, stream>>>(z, r0, pcur, Apb, scal, it);
    }
  }
}

// Round 4
// 658.484 us; speedup vs baseline: 2.9363x; 2.9363x over previous
//
#include <hip/hip_runtime.h>
#include <math.h>

#define HW 65536
#define NC 10
#define NT 12
#define LAMBDA_F 0.05f
#define PI_F 3.14159265358979323846f
// XOR-swizzle for wave-private LDS fft scratch
#define SWZ(i) ((i) ^ ((i) >> 4))

__device__ __forceinline__ float2 cadd(float2 a, float2 b){ return make_float2(a.x+b.x, a.y+b.y); }
__device__ __forceinline__ float2 csub(float2 a, float2 b){ return make_float2(a.x-b.x, a.y-b.y); }
__device__ __forceinline__ float2 cmul(float2 a, float2 b){ return make_float2(a.x*b.x-a.y*b.y, a.x*b.y+a.y*b.x); }
// conj(a)*b
__device__ __forceinline__ float2 cmulj(float2 a, float2 b){ return make_float2(a.x*b.x+a.y*b.y, a.x*b.y-a.y*b.x); }
__device__ __forceinline__ float2 cscale(float2 a, float s){ return make_float2(a.x*s, a.y*s); }

template<int SIGN>
__device__ __forceinline__ void radix4_nt(float2& a0, float2& a1, float2& a2, float2& a3){
  float2 t0=cadd(a0,a2), t1=csub(a0,a2), t2=cadd(a1,a3), t3=csub(a1,a3);
  float2 t3r;
  if constexpr (SIGN < 0) t3r = make_float2(t3.y, -t3.x); else t3r = make_float2(-t3.y, t3.x);
  a0=cadd(t0,t2); a1=cadd(t1,t3r); a2=csub(t0,t2); a3=csub(t1,t3r);
}

template<int SIGN>
__device__ __forceinline__ float2 twl(const float2* tw, int e){
  float2 w = tw[e];
  if constexpr (SIGN > 0) w.y = -w.y;
  return w;
}

template<int SIGN>
__device__ __forceinline__ void radix4_tw(float2& a0, float2& a1, float2& a2, float2& a3,
                                          const float2* tw, int e){
  float2 w1 = twl<SIGN>(tw, e);
  float2 w2 = cmul(w1, w1);
  float2 w3 = cmul(w1, w2);
  a1 = cmul(a1, w1); a2 = cmul(a2, w2); a3 = cmul(a3, w3);
  radix4_nt<SIGN>(a0, a1, a2, a3);
}

// 256-pt Stockham radix-4 FFT, natural order in/out, unnormalized.
// BARRIER-FREE: b0/b1 must be private to the calling wave (64 lanes).
template<int SIGN>
__device__ __forceinline__ void fft256(float2* b0, float2* b1, const float2* tw, int j,
                                       float2& x0, float2& x1, float2& x2, float2& x3){
  radix4_nt<SIGN>(x0,x1,x2,x3);
  b0[SWZ(4*j)]=x0; b0[SWZ(4*j+1)]=x1; b0[SWZ(4*j+2)]=x2; b0[SWZ(4*j+3)]=x3;
  __builtin_amdgcn_sched_barrier(0);
  x0=b0[SWZ(j)]; x1=b0[SWZ(j+64)]; x2=b0[SWZ(j+128)]; x3=b0[SWZ(j+192)];
  __builtin_amdgcn_sched_barrier(0);
  radix4_tw<SIGN>(x0,x1,x2,x3, tw, (j&3)<<4);
  { int i=((j>>2)<<4)+(j&3); b1[SWZ(i)]=x0; b1[SWZ(i+4)]=x1; b1[SWZ(i+8)]=x2; b1[SWZ(i+12)]=x3; }
  __builtin_amdgcn_sched_barrier(0);
  x0=b1[SWZ(j)]; x1=b1[SWZ(j+64)]; x2=b1[SWZ(j+128)]; x3=b1[SWZ(j+192)];
  __builtin_amdgcn_sched_barrier(0);
  radix4_tw<SIGN>(x0,x1,x2,x3, tw, (j&15)<<2);
  { int i=((j>>4)<<6)+(j&15); b0[SWZ(i)]=x0; b0[SWZ(i+16)]=x1; b0[SWZ(i+32)]=x2; b0[SWZ(i+48)]=x3; }
  __builtin_amdgcn_sched_barrier(0);
  x0=b0[SWZ(j)]; x1=b0[SWZ(j+64)]; x2=b0[SWZ(j+128)]; x3=b0[SWZ(j+192)];
  __builtin_amdgcn_sched_barrier(0);
  radix4_tw<SIGN>(x0,x1,x2,x3, tw, j);
}

__device__ __forceinline__ void tw_init(float2* tw, int tid){
  float s, c;
  __sincosf(-2.0f*PI_F*(float)tid*(1.0f/256.0f), &s, &c);
  tw[tid] = make_float2(c, s);
}

// ---------- S0: W9 precompute + g = D*sum_t conj(L) y (into bufB) + scal zero
__global__ __launch_bounds__(256) void k_setup(const float* __restrict__ mask,
                                               const float2* __restrict__ Lt,
                                               const float2* __restrict__ y,
                                               float* __restrict__ W9,
                                               float2* __restrict__ bufB,
                                               float* __restrict__ scal){
  int tid = threadIdx.x;
  int u = blockIdx.x;
  if (u == 0 && tid < 128) scal[tid] = 0.0f;
  if (u < 256){
    int kx = u, ky = tid;
    int mx = (kx + 128) & 255, my = (ky + 128) & 255;
    float d0=0.f,d1=0.f,d2=0.f;
    float2 o01=make_float2(0,0), o02=make_float2(0,0), o12=make_float2(0,0);
    for (int t = 0; t < NT; t++){
      float m = mask[t*HW + my*256 + mx];
      float2 l0 = Lt[t*3+0], l1 = Lt[t*3+1], l2 = Lt[t*3+2];
      d0 += m*(l0.x*l0.x + l0.y*l0.y);
      d1 += m*(l1.x*l1.x + l1.y*l1.y);
      d2 += m*(l2.x*l2.x + l2.y*l2.y);
      o01 = cadd(o01, cscale(cmulj(l0,l1), m));
      o02 = cadd(o02, cscale(cmulj(l0,l2), m));
      o12 = cadd(o12, cscale(cmulj(l1,l2), m));
    }
    const float nrm = 1.0f/65536.0f;
    int idx = kx*256 + ky;
    W9[idx]      = d0*nrm;  W9[idx+HW]   = d1*nrm;  W9[idx+2*HW] = d2*nrm;
    W9[idx+3*HW] = o01.x*nrm; W9[idx+4*HW] = o01.y*nrm;
    W9[idx+5*HW] = o02.x*nrm; W9[idx+6*HW] = o02.y*nrm;
    W9[idx+7*HW] = o12.x*nrm; W9[idx+8*HW] = o12.y*nrm;
  } else {
    int idx = (u-256)*256 + tid;
    int c = idx >> 16, pix = idx & (HW-1);
    int xx = pix & 255, yy2 = pix >> 8;
    float sg = ((xx + yy2) & 1) ? -1.0f : 1.0f;
    float2 a0=make_float2(0,0), a1=make_float2(0,0), a2=make_float2(0,0);
    for (int t = 0; t < NT; t++){
      float2 yv = y[((size_t)(t*NC + c))*HW + pix];
      a0 = cadd(a0, cmulj(Lt[t*3+0], yv));
      a1 = cadd(a1, cmulj(Lt[t*3+1], yv));
      a2 = cadd(a2, cmulj(Lt[t*3+2], yv));
    }
    bufB[((size_t)(c*3+0))*HW + pix] = cscale(a0, sg);
    bufB[((size_t)(c*3+1))*HW + pix] = cscale(a1, sg);
    bufB[((size_t)(c*3+2))*HW + pix] = cscale(a2, sg);
  }
}

// ---------- setup row IFFT (-1): bufB row-major -> bufA transposed [pl][kx][y]
__global__ __launch_bounds__(256) void k_rows_plain(const float2* __restrict__ src,
                                                    float2* __restrict__ dst){
  __shared__ float2 tile[8][256];
  __shared__ float2 sc[4][256];
  __shared__ float2 tw[256];
  int tid = threadIdx.x, g = tid >> 6, j = tid & 63;
  tw_init(tw, tid);
  __syncthreads();
  int pl = blockIdx.y, ri = blockIdx.x;
  const float2* s = src + (size_t)pl*HW;
  for (int rr = 0; rr < 2; rr++){
    int lr = g + rr*4, row = ri*8 + lr;
    const float2* sr = s + row*256;
    float2 x0=sr[j], x1=sr[j+64], x2=sr[j+128], x3=sr[j+192];
    fft256<-1>(tile[lr], sc[g], tw, j, x0,x1,x2,x3);
    tile[lr][j]=x0; tile[lr][j+64]=x1; tile[lr][j+128]=x2; tile[lr][j+192]=x3;
  }
  __syncthreads();
  float2* dT = dst + (size_t)pl*HW;
  int yo2 = (tid&3)*2, kxo = tid>>2;
  #pragma unroll
  for (int kb = 0; kb < 4; kb++){
    int kx = kb*64 + kxo;
    float2 a = tile[yo2][kx], b = tile[yo2+1][kx];
    *(float4*)(dT + (size_t)kx*256 + ri*8 + yo2) = make_float4(a.x,a.y,b.x,b.y);
  }
}

// ---------- setup col IFFT (-1): bufA [pl][kx][y] contiguous -> bufB row-major
__global__ __launch_bounds__(256) void k_cols_plain(const float2* __restrict__ src,
                                                    float2* __restrict__ dst){
  __shared__ float2 tile[4][256];
  __shared__ float2 sc[4][256];
  __shared__ float2 tw[256];
  int tid = threadIdx.x, g = tid >> 6, j = tid & 63;
  tw_init(tw, tid);
  __syncthreads();
  int pl = blockIdx.y, kg = blockIdx.x;
  int kx = kg*4 + g;
  const float2* col = src + (size_t)pl*HW + (size_t)kx*256;
  float2 x0=col[j], x1=col[j+64], x2=col[j+128], x3=col[j+192];
  fft256<-1>(tile[g], sc[g], tw, j, x0,x1,x2,x3);
  tile[g][j]=x0; tile[g][j+64]=x1; tile[g][j+128]=x2; tile[g][j+192]=x3;
  __syncthreads();
  float2* d = dst + (size_t)pl*HW;
  int kxo2 = (tid&1)*2, yy = tid>>1;
  #pragma unroll
  for (int yb = 0; yb < 2; yb++){
    int yc = yb*128 + yy;
    float2 a = tile[kxo2][yc], b = tile[kxo2+1][yc];
    *(float4*)(d + (size_t)yc*256 + kg*4 + kxo2) = make_float4(a.x,a.y,b.x,b.y);
  }
}

// ---------- b = D * sum_c conj(S_c) * bufB + lambda*mo ; p=r=b ; z=0 ; rs0
__global__ __launch_bounds__(256) void k_compute_b(const float2* __restrict__ A,
                                                   const float2* __restrict__ sens,
                                                   const float2* __restrict__ mo,
                                                   float2* __restrict__ p,
                                                   float2* __restrict__ r,
                                                   float2* __restrict__ z,
                                                   float* __restrict__ scal){
  __shared__ float red[4];
  int idx = blockIdx.x*256 + threadIdx.x;
  int s = idx >> 16, pix = idx & (HW-1);
  int xx = pix & 255, yy = pix >> 8;
  float sg = ((xx + yy) & 1) ? -1.0f : 1.0f;
  float2 accv = make_float2(0,0);
  for (int c = 0; c < NC; c++)
    accv = cadd(accv, cmulj(sens[(size_t)c*HW + pix], A[((size_t)(c*3+s))*HW + pix]));
  float2 b = cadd(cscale(accv, sg), cscale(mo[idx], LAMBDA_F));
  p[idx] = b; r[idx] = b; z[idx] = make_float2(0,0);
  float part = b.x*b.x + b.y*b.y;
  for (int off = 32; off; off >>= 1) part += __shfl_down(part, off);
  int j = threadIdx.x & 63, w = threadIdx.x >> 6;
  if (j == 0) red[w] = part;
  __syncthreads();
  if (threadIdx.x == 0) atomicAdd(&scal[0], red[0]+red[1]+red[2]+red[3]);
}

// ---------- A: p-update fused + sens-mult + row FFT (+1) -> bufA transposed
__global__ __launch_bounds__(256) void k_rows_op(const float2* __restrict__ rbuf,
                                                 const float2* __restrict__ pprev,
                                                 float2* __restrict__ pout,
                                                 const float2* __restrict__ sens,
                                                 float2* __restrict__ dst,
                                                 const float* __restrict__ scal, int iter){
  __shared__ float2 tile[8][256];
  __shared__ float2 sc[4][256];
  __shared__ float2 tw[256];
  int tid = threadIdx.x, g = tid >> 6, j = tid & 63;
  tw_init(tw, tid);
  __syncthreads();
  int pl = blockIdx.y, ri = blockIdx.x;
  int c = pl/3, sp = pl - 3*c;
  const float2* Sp = sens + (size_t)c*HW;
  for (int rr = 0; rr < 2; rr++){
    int lr = g + rr*4, row = ri*8 + lr;
    int base = row*256;
    size_t pb = (size_t)sp*HW + base;
    float2 pv0, pv1, pv2, pv3;
    if (iter == 0){
      pv0 = pprev[pb+j]; pv1 = pprev[pb+j+64]; pv2 = pprev[pb+j+128]; pv3 = pprev[pb+j+192];
    } else {
      float beta = scal[iter] / scal[iter-1];
      pv0 = cadd(rbuf[pb+j],     cscale(pprev[pb+j],     beta));
      pv1 = cadd(rbuf[pb+j+64],  cscale(pprev[pb+j+64],  beta));
      pv2 = cadd(rbuf[pb+j+128], cscale(pprev[pb+j+128], beta));
      pv3 = cadd(rbuf[pb+j+192], cscale(pprev[pb+j+192], beta));
      if (c == 0){
        pout[pb+j] = pv0; pout[pb+j+64] = pv1; pout[pb+j+128] = pv2; pout[pb+j+192] = pv3;
      }
    }
    float2 x0 = cmul(Sp[base+j],     pv0);
    float2 x1 = cmul(Sp[base+j+64],  pv1);
    float2 x2 = cmul(Sp[base+j+128], pv2);
    float2 x3 = cmul(Sp[base+j+192], pv3);
    fft256<1>(tile[lr], sc[g], tw, j, x0,x1,x2,x3);
    tile[lr][j]=x0; tile[lr][j+64]=x1; tile[lr][j+128]=x2; tile[lr][j+192]=x3;
  }
  __syncthreads();
  float2* dT = dst + (size_t)pl*HW;
  int yo2 = (tid&3)*2, kxo = tid>>2;
  #pragma unroll
  for (int kb = 0; kb < 4; kb++){
    int kx = kb*64 + kxo;
    float2 a = tile[yo2][kx], b = tile[yo2+1][kx];
    *(float4*)(dT + (size_t)kx*256 + ri*8 + yo2) = make_float4(a.x,a.y,b.x,b.y);
  }
}

// ---------- B: col FFT(+1) -> 3x3 W -> col IFFT(-1); bufA contiguous -> bufB row-major
__global__ __launch_bounds__(256) void k_cols_W(const float2* __restrict__ src,
                                                float2* __restrict__ dst,
                                                const float* __restrict__ W9){
  __shared__ float2 tile[12][256];   // out-staging: [s*4+g][y]
  __shared__ float2 sc[4][256];
  __shared__ float2 tw[256];
  int tid = threadIdx.x, g = tid >> 6, j = tid & 63;
  tw_init(tw, tid);
  __syncthreads();
  int kg = blockIdx.x, c = blockIdx.y;
  int kx = kg*4 + g;
  // forward col FFT per sv plane (direct contiguous reads)
  float2 X[3][4];
  #pragma unroll
  for (int s = 0; s < 3; s++){
    const float2* col = src + ((size_t)(c*3+s))*HW + (size_t)kx*256;
    float2 x0=col[j], x1=col[j+64], x2=col[j+128], x3=col[j+192];
    fft256<1>(tile[s*4+g], sc[g], tw, j, x0,x1,x2,x3);
    X[s][0]=x0; X[s][1]=x1; X[s][2]=x2; X[s][3]=x3;
  }
  // W combine
  float2 U[3][4];
  #pragma unroll
  for (int q = 0; q < 4; q++){
    int wi = kx*256 + j + 64*q;
    float d0 = W9[wi], d1 = W9[wi+HW], d2 = W9[wi+2*HW];
    float2 o01 = make_float2(W9[wi+3*HW], W9[wi+4*HW]);
    float2 o02 = make_float2(W9[wi+5*HW], W9[wi+6*HW]);
    float2 o12 = make_float2(W9[wi+7*HW], W9[wi+8*HW]);
    float2 v0 = X[0][q], v1 = X[1][q], v2 = X[2][q];
    U[0][q] = cadd(cadd(cscale(v0,d0), cmul(o01,v1)), cmul(o02,v2));
    U[1][q] = cadd(cadd(cmulj(o01,v0), cscale(v1,d1)), cmul(o12,v2));
    U[2][q] = cadd(cadd(cmulj(o02,v0), cmulj(o12,v1)), cscale(v2,d2));
  }
  // inverse col FFT, stage into tile
  #pragma unroll
  for (int s = 0; s < 3; s++){
    float2 x0=U[s][0], x1=U[s][1], x2=U[s][2], x3=U[s][3];
    fft256<-1>(tile[s*4+g], sc[g], tw, j, x0,x1,x2,x3);
    tile[s*4+g][j]=x0; tile[s*4+g][j+64]=x1; tile[s*4+g][j+128]=x2; tile[s*4+g][j+192]=x3;
  }
  __syncthreads();
  // transpose-write row-major (32B chunks)
  int kxo2 = (tid&1)*2, yy = tid>>1;
  for (int s = 0; s < 3; s++){
    float2* d = dst + ((size_t)(c*3+s))*HW;
    #pragma unroll
    for (int yb = 0; yb < 2; yb++){
      int yc = yb*128 + yy;
      float2 a = tile[s*4+kxo2][yc], b = tile[s*4+kxo2+1][yc];
      *(float4*)(d + (size_t)yc*256 + kg*4 + kxo2) = make_float4(a.x,a.y,b.x,b.y);
    }
  }
}

// ---------- C: row IFFT(-1) + conj(S) coil-combine + lambda*p -> Ap; pAp reduce
__global__ __launch_bounds__(256) void k_rows_acc(const float2* __restrict__ Bp,
                                                  const float2* __restrict__ sens,
                                                  const float2* __restrict__ p,
                                                  float2* __restrict__ Ap,
                                                  float* __restrict__ scal, int iter){
  __shared__ float2 lds0[4][256], lds1[4][256];
  __shared__ float2 acc[4][256];
  __shared__ float2 tw[256];
  __shared__ float2 wred[4];
  int tid = threadIdx.x, g = tid >> 6, j = tid & 63;
  tw_init(tw, tid);
  __syncthreads();
  int row = blockIdx.x, s = blockIdx.y;
  acc[g][j]=make_float2(0,0); acc[g][j+64]=make_float2(0,0);
  acc[g][j+128]=make_float2(0,0); acc[g][j+192]=make_float2(0,0);
  for (int cc = 0; cc < 3; cc++){
    int c = cc*4 + g;
    if (c < NC){
      size_t base = ((size_t)(c*3+s))*HW + row*256;
      float2 x0 = Bp[base+j], x1 = Bp[base+j+64], x2 = Bp[base+j+128], x3 = Bp[base+j+192];
      fft256<-1>(lds0[g], lds1[g], tw, j, x0,x1,x2,x3);
      size_t sb = (size_t)c*HW + row*256;
      acc[g][j]     = cadd(acc[g][j],     cmulj(sens[sb+j],     x0));
      acc[g][j+64]  = cadd(acc[g][j+64],  cmulj(sens[sb+j+64],  x1));
      acc[g][j+128] = cadd(acc[g][j+128], cmulj(sens[sb+j+128], x2));
      acc[g][j+192] = cadd(acc[g][j+192], cmulj(sens[sb+j+192], x3));
    }
  }
  __syncthreads();
  int k = tid;
  size_t ob = (size_t)s*HW + row*256 + k;
  float2 a = cadd(cadd(acc[0][k], acc[1][k]), cadd(acc[2][k], acc[3][k]));
  float2 pv = p[ob];
  float2 ap = cadd(a, cscale(pv, LAMBDA_F));
  Ap[ob] = ap;
  float2 pap = cmulj(pv, ap);
  for (int off = 32; off; off >>= 1){
    pap.x += __shfl_down(pap.x, off);
    pap.y += __shfl_down(pap.y, off);
  }
  if (j == 0) wred[g] = pap;
  __syncthreads();
  if (tid == 0){
    float2 tot = cadd(cadd(wred[0], wred[1]), cadd(wred[2], wred[3]));
    atomicAdd(&scal[16 + 2*iter],     tot.x);
    atomicAdd(&scal[16 + 2*iter + 1], tot.y);
  }
}

// ---------- D: z += alpha p ; r -= alpha Ap ; rs[i+1] += |r|^2
__global__ __launch_bounds__(256) void k_update_zr(float2* __restrict__ z,
                                                   float2* __restrict__ r,
                                                   const float2* __restrict__ p,
                                                   const float2* __restrict__ Ap,
                                                   float* __restrict__ scal, int iter){
  __shared__ float red[4];
  int idx = blockIdx.x*256 + threadIdx.x;
  float rs = scal[iter];
  float2 pap = make_float2(scal[16+2*iter], scal[16+2*iter+1]);
  float den = pap.x*pap.x + pap.y*pap.y;
  float inv = rs / den;
  float2 alpha = make_float2(pap.x*inv, -pap.y*inv);
  float2 pv = p[idx], apv = Ap[idx];
  float2 zv = cadd(z[idx], cmul(alpha, pv));
  float2 rv = csub(r[idx], cmul(alpha, apv));
  z[idx] = zv; r[idx] = rv;
  float part = rv.x*rv.x + rv.y*rv.y;
  for (int off = 32; off; off >>= 1) part += __shfl_down(part, off);
  int j = threadIdx.x & 63, w = threadIdx.x >> 6;
  if (j == 0) red[w] = part;
  __syncthreads();
  if (threadIdx.x == 0) atomicAdd(&scal[iter+1], red[0]+red[1]+red[2]+red[3]);
}

extern "C" void kernel_launch(void* const* d_in, const int* in_sizes, int n_in,
                              void* d_out, int out_size, void* d_ws, size_t ws_size,
                              hipStream_t stream){
  const float2* y    = (const float2*)d_in[0];
  const float2* mo   = (const float2*)d_in[1];
  const float2* sens = (const float2*)d_in[2];
  const float2* Lt   = (const float2*)d_in[3];
  const float*  mask = (const float*)d_in[4];

  float* w = (float*)d_ws;
  float*  scal = w;                                  // 128 floats
  float*  W9   = w + 128;                            // 9*HW floats
  float2* bufA = (float2*)(w + 128 + 9*HW);          // 30 planes (transposed k-space)
  float2* bufB = bufA + (size_t)30*HW;               // 30 planes (row-major)
  float2* p0   = bufB + (size_t)30*HW;
  float2* p1   = p0 + (size_t)3*HW;
  float2* r    = p1 + (size_t)3*HW;
  float2* Ap   = r  + (size_t)3*HW;
  float2* z    = (float2*)d_out;

  // setup
  k_setup<<<2816, 256, 0, stream>>>(mask, Lt, y, W9, bufB, scal);
  k_rows_plain<<<dim3(32, 30), 256, 0, stream>>>(bufB, bufA);
  k_cols_plain<<<dim3(64, 30), 256, 0, stream>>>(bufA, bufB);
  k_compute_b<<<768, 256, 0, stream>>>(bufB, sens, mo, p0, r, z, scal);

  // CG iterations
  for (int it = 0; it < 10; it++){
    float2* pcur  = (it & 1) ? p1 : p0;
    float2* pprev = (it == 0) ? p0 : ((it & 1) ? p0 : p1);
    k_rows_op<<<dim3(32, 30), 256, 0, stream>>>(r, pprev, pcur, sens, bufA, scal, it);
    k_cols_W<<<dim3(64, 10), 256, 0, stream>>>(bufA, bufB, W9);
    k_rows_acc<<<dim3(256, 3), 256, 0, stream>>>(bufB, sens, pcur, Ap, scal, it);
    k_update_zr<<<768, 256, 0, stream>>>(z, r, pcur, Ap, scal, it);
  }
}